// Round 2
// baseline (286.563 us; speedup 1.0000x reference)
//
#include <hip/hip_runtime.h>
#include <math.h>

#define DELTA 0.1f
constexpr int BLOCK = 256;
constexpr int RPT   = 5;   // rows per thread; 4,000,000 = 3125 blocks * 256 thr * 5

__device__ __forceinline__ float row_loss(float4 p, float4 t) {
    float mp = (p.x + p.y + p.z + p.w) * 0.25f;
    float mt = (t.x + t.y + t.z + t.w) * 0.25f;
    float dpx = p.x - mp, dpy = p.y - mp, dpz = p.z - mp, dpw = p.w - mp;
    float dtx = t.x - mt, dty = t.y - mt, dtz = t.z - mt, dtw = t.w - mt;
    const float inv = 1.0f / 3.0f;  // 1/(D-1)
    float vp  = (dpx*dpx + dpy*dpy + dpz*dpz + dpw*dpw) * inv;
    float vt  = (dtx*dtx + dty*dty + dtz*dtz + dtw*dtw) * inv;
    float cov = (dpx*dtx + dpy*dty + dpz*dtz + dpw*dtw) * inv;
    float a1 = 2.0f * mp * mt + DELTA;
    float a2 = 2.0f * cov + DELTA;
    float b1 = mp * mp + mt * mt + DELTA;
    float b2 = vp + vt + DELTA;
    return 1.0f - (a1 * a2) / (b1 * b2 + DELTA);
}

__global__ __launch_bounds__(BLOCK, 8) void ssim_loss_kernel(
    const float4* __restrict__ pred,
    const float4* __restrict__ target,
    double* __restrict__ accum,
    unsigned int* __restrict__ counter,
    float* __restrict__ out,
    int N)
{
    const int S    = gridDim.x * BLOCK;
    const int gtid = blockIdx.x * BLOCK + threadIdx.x;

    float local = 0.0f;

    if (RPT * S <= N) {  // uniform branch; true for the bench shape
        // Issue all 10 loads before any compute: 160 B/lane in flight,
        // one latency exposure instead of five.
        float4 p[RPT], t[RPT];
        #pragma unroll
        for (int k = 0; k < RPT; ++k) {
            p[k] = pred[gtid + k * S];
            t[k] = target[gtid + k * S];
        }
        #pragma unroll
        for (int k = 0; k < RPT; ++k)
            local += row_loss(p[k], t[k]);
        // Remainder rows (none when N % (BLOCK*RPT*grid) == 0).
        for (int i = RPT * S + gtid; i < N; i += S)
            local += row_loss(pred[i], target[i]);
    } else {
        for (int i = gtid; i < N; i += S)
            local += row_loss(pred[i], target[i]);
    }

    // Wave64 reduce.
    #pragma unroll
    for (int off = 32; off > 0; off >>= 1)
        local += __shfl_down(local, off, 64);

    __shared__ float wave_sums[BLOCK / 64];
    int lane = threadIdx.x & 63;
    int wid  = threadIdx.x >> 6;
    if (lane == 0) wave_sums[wid] = local;
    __syncthreads();

    if (threadIdx.x == 0) {
        float s = wave_sums[0] + wave_sums[1] + wave_sums[2] + wave_sums[3];
        atomicAdd(accum, (double)s);          // device-scope
        __threadfence();
        unsigned int done = atomicAdd(counter, 1u);
        if (done == gridDim.x - 1) {          // last block finalizes (no 2nd launch)
            __threadfence();
            double total = atomicAdd(accum, 0.0);  // coherent read
            float f = (float)(total / (double)N);
            if (isnan(f)) f = 1.0f;           // reference NaN fallback == 1.0
            *out = f;
        }
    }
}

extern "C" void kernel_launch(void* const* d_in, const int* in_sizes, int n_in,
                              void* d_out, int out_size, void* d_ws, size_t ws_size,
                              hipStream_t stream)
{
    const float4* pred   = (const float4*)d_in[0];
    const float4* target = (const float4*)d_in[1];
    int rows = in_sizes[0] / 4;

    double*       accum   = (double*)d_ws;
    unsigned int* counter = (unsigned int*)((char*)d_ws + 8);
    hipMemsetAsync(d_ws, 0, 16, stream);  // accum + counter (ws is poisoned 0xAA)

    int grid = rows / (BLOCK * RPT);      // 3125 for 4M rows
    if (grid < 1) grid = 1;
    ssim_loss_kernel<<<grid, BLOCK, 0, stream>>>(pred, target, accum, counter,
                                                 (float*)d_out, rows);
}

// Round 3
// 144.722 us; speedup vs baseline: 1.9801x; 1.9801x over previous
//
#include <hip/hip_runtime.h>
#include <math.h>

#define DELTA 0.1f
constexpr int BLOCK = 256;
constexpr int RPT   = 5;   // 4,000,000 rows = 3125 blocks * 256 thr * 5

__device__ __forceinline__ float row_loss(float4 p, float4 t) {
    float mp = (p.x + p.y + p.z + p.w) * 0.25f;
    float mt = (t.x + t.y + t.z + t.w) * 0.25f;
    float dpx = p.x - mp, dpy = p.y - mp, dpz = p.z - mp, dpw = p.w - mp;
    float dtx = t.x - mt, dty = t.y - mt, dtz = t.z - mt, dtw = t.w - mt;
    const float inv = 1.0f / 3.0f;  // 1/(D-1)
    float vp  = (dpx*dpx + dpy*dpy + dpz*dpz + dpw*dpw) * inv;
    float vt  = (dtx*dtx + dty*dty + dtz*dtz + dtw*dtw) * inv;
    float cov = (dpx*dtx + dpy*dty + dpz*dtz + dpw*dtw) * inv;
    float a1 = 2.0f * mp * mt + DELTA;
    float a2 = 2.0f * cov + DELTA;
    float b1 = mp * mp + mt * mt + DELTA;
    float b2 = vp + vt + DELTA;
    return 1.0f - (a1 * a2) / (b1 * b2 + DELTA);
}

// No atomics, no fences: each block writes its partial to a distinct slot.
__global__ __launch_bounds__(BLOCK) void ssim_partial_kernel(
    const float4* __restrict__ pred,
    const float4* __restrict__ target,
    float* __restrict__ partials,
    int N)
{
    const int S    = gridDim.x * BLOCK;
    const int gtid = blockIdx.x * BLOCK + threadIdx.x;

    float local = 0.0f;

    if (RPT * S <= N) {  // uniform branch; exact for the bench shape
        float4 p[RPT], t[RPT];
        #pragma unroll
        for (int k = 0; k < RPT; ++k) {
            p[k] = pred[gtid + k * S];
            t[k] = target[gtid + k * S];
        }
        #pragma unroll
        for (int k = 0; k < RPT; ++k)
            local += row_loss(p[k], t[k]);
        for (int i = RPT * S + gtid; i < N; i += S)   // remainder (empty at 4M)
            local += row_loss(pred[i], target[i]);
    } else {
        for (int i = gtid; i < N; i += S)
            local += row_loss(pred[i], target[i]);
    }

    #pragma unroll
    for (int off = 32; off > 0; off >>= 1)
        local += __shfl_down(local, off, 64);

    __shared__ float wave_sums[BLOCK / 64];
    int lane = threadIdx.x & 63;
    int wid  = threadIdx.x >> 6;
    if (lane == 0) wave_sums[wid] = local;
    __syncthreads();

    if (threadIdx.x == 0)
        partials[blockIdx.x] = wave_sums[0] + wave_sums[1]
                             + wave_sums[2] + wave_sums[3];
}

// One block reduces all per-block partials in f64, applies mean + NaN fallback.
__global__ __launch_bounds__(BLOCK) void ssim_finalize_kernel(
    const float* __restrict__ partials, int nparts,
    float* __restrict__ out, int N)
{
    double local = 0.0;
    for (int i = threadIdx.x; i < nparts; i += BLOCK)
        local += (double)partials[i];

    #pragma unroll
    for (int off = 32; off > 0; off >>= 1)
        local += __shfl_down(local, off, 64);

    __shared__ double wave_sums[BLOCK / 64];
    int lane = threadIdx.x & 63;
    int wid  = threadIdx.x >> 6;
    if (lane == 0) wave_sums[wid] = local;
    __syncthreads();

    if (threadIdx.x == 0) {
        double total = wave_sums[0] + wave_sums[1] + wave_sums[2] + wave_sums[3];
        float f = (float)(total / (double)N);
        if (isnan(f)) f = 1.0f;   // reference NaN fallback == mean(ones) == 1.0
        *out = f;
    }
}

extern "C" void kernel_launch(void* const* d_in, const int* in_sizes, int n_in,
                              void* d_out, int out_size, void* d_ws, size_t ws_size,
                              hipStream_t stream)
{
    const float4* pred   = (const float4*)d_in[0];
    const float4* target = (const float4*)d_in[1];
    int rows = in_sizes[0] / 4;

    int grid = (rows + BLOCK * RPT - 1) / (BLOCK * RPT);  // 3125 at 4M rows
    if (grid < 1) grid = 1;

    float* partials = (float*)d_ws;  // grid * 4 B; every slot overwritten each call

    ssim_partial_kernel<<<grid, BLOCK, 0, stream>>>(pred, target, partials, rows);
    ssim_finalize_kernel<<<1, BLOCK, 0, stream>>>(partials, grid, (float*)d_out, rows);
}